// Round 8
// baseline (421.019 us; speedup 1.0000x reference)
//
#include <hip/hip_runtime.h>

// Segment-mean ("centers") via bin-then-gather (no atomics on the heavy pass).
// inputs: [N, D] f32, targets: [N] i32, classes: scalar (derived), class_weight: [C, D] f32
// out: [C, D] f32
// ws: counts i32[C] | cursors i32[C] | offsets i32[C] | binned i32[N] | part f32[SPLIT*C*D]
//
// Time budget (MI355X): harness reset (1 GiB ws poison + 252 MB input restore)
// ~290 us is charged into dur_us and is not controllable. Our chain floor:
// gather ~41 us (256 MB @ 6.3 TB/s) + ~15 us bookkeeping.

typedef float floatx4 __attribute__((ext_vector_type(4)));

#define SPLIT 4   // blocks per class in the gather pass

// Fused bookkeeping: zero + LDS histogram + exclusive scan + cursor init.
// One block, 1024 threads (C <= 1024). Replaces 3 kernels.
__global__ void hist_scan_kernel(const int* __restrict__ targets, int n, int c,
                                 int* __restrict__ counts,
                                 int* __restrict__ offsets,
                                 int* __restrict__ cursors) {
    __shared__ int h[1024];
    __shared__ int buf[2][1024];
    int tid = threadIdx.x;
    h[tid] = 0;
    __syncthreads();
    for (int i = tid; i < n; i += 1024) atomicAdd(&h[targets[i]], 1);
    __syncthreads();
    int v = h[tid];                          // tid >= c reads 0 (never touched)
    buf[0][tid] = v;
    __syncthreads();
    int src = 0;
    for (int d = 1; d < 1024; d <<= 1) {     // inclusive Hillis-Steele scan
        int x = buf[src][tid];
        if (tid >= d) x += buf[src][tid - d];
        buf[src ^ 1][tid] = x;
        src ^= 1;
        __syncthreads();
    }
    if (tid < c) {
        int excl = buf[src][tid] - v;        // exclusive prefix
        counts[tid]  = v;
        offsets[tid] = excl;
        cursors[tid] = excl;                 // scatter bumps from here
    }
}

__global__ void scatter_kernel(const int* __restrict__ targets,
                               int* __restrict__ cursors,
                               int* __restrict__ binned, int n) {
    int i = blockIdx.x * blockDim.x + threadIdx.x;
    if (i < n) {
        int pos = atomicAdd(&cursors[targets[i]], 1);   // cursor pre-seeded with offset
        binned[pos] = i;
    }
}

// SPLIT blocks per class; 256 threads x float4 = full 4 KB row per iteration.
// 4000 blocks -> ~16/CU, good balance; plain (cached) loads — m13's 6.29 TB/s
// ceiling was measured with plain float4 loads, so no nontemporal here.
__global__ void gather_kernel(const floatx4* __restrict__ in4,
                              const int* __restrict__ counts,
                              const int* __restrict__ offsets,
                              const int* __restrict__ binned,
                              floatx4* __restrict__ part4, int d4) {
    int b = blockIdx.x;
    int c = b >> 2, q = b & 3;                 // SPLIT==4
    int cnt = counts[c];
    if (cnt == 0) return;                      // finalize uses class_weight
    int begin = (cnt * q) >> 2;
    int end   = (cnt * (q + 1)) >> 2;
    int off = offsets[c] + begin;
    int m = end - begin;                       // may be 0; then writes zeros
    int tid = threadIdx.x;                     // 0..255 == d4

    __shared__ int rows[1024];
    floatx4 a0 = {0,0,0,0}, a1 = {0,0,0,0}, a2 = {0,0,0,0}, a3 = {0,0,0,0};
    floatx4 a4 = {0,0,0,0}, a5 = {0,0,0,0}, a6 = {0,0,0,0}, a7 = {0,0,0,0};

    for (int base = 0; base < m; base += 1024) {
        int mm = min(m - base, 1024);
        __syncthreads();
        for (int j = tid; j < mm; j += blockDim.x) rows[j] = binned[off + base + j];
        __syncthreads();
        int j = 0;
        for (; j + 7 < mm; j += 8) {           // 8 independent load chains
            int r0 = rows[j],   r1 = rows[j+1], r2 = rows[j+2], r3 = rows[j+3];
            int r4 = rows[j+4], r5 = rows[j+5], r6 = rows[j+6], r7 = rows[j+7];
            a0 += in4[(size_t)r0 * d4 + tid];
            a1 += in4[(size_t)r1 * d4 + tid];
            a2 += in4[(size_t)r2 * d4 + tid];
            a3 += in4[(size_t)r3 * d4 + tid];
            a4 += in4[(size_t)r4 * d4 + tid];
            a5 += in4[(size_t)r5 * d4 + tid];
            a6 += in4[(size_t)r6 * d4 + tid];
            a7 += in4[(size_t)r7 * d4 + tid];
        }
        for (; j < mm; ++j)
            a0 += in4[(size_t)rows[j] * d4 + tid];
    }
    floatx4 s = ((a0 + a1) + (a2 + a3)) + ((a4 + a5) + (a6 + a7));
    part4[(size_t)b * d4 + tid] = s;           // partial sum for this quarter
}

// One block per class: combine SPLIT partials, divide by count, or fall back.
__global__ void finalize_kernel(const floatx4* __restrict__ part4,
                                const floatx4* __restrict__ w4,
                                const int* __restrict__ counts,
                                floatx4* __restrict__ out4, int d4) {
    int c = blockIdx.x;
    int tid = threadIdx.x;
    int cnt = counts[c];
    size_t o = (size_t)c * d4 + tid;
    floatx4 r;
    if (cnt > 0) {
        size_t pb = (size_t)(c << 2) * d4 + tid;
        floatx4 s = (part4[pb] + part4[pb + d4])
                  + (part4[pb + 2 * d4] + part4[pb + 3 * d4]);
        r = s * (1.0f / (float)cnt);
    } else {
        r = w4[o];
    }
    out4[o] = r;
}

extern "C" void kernel_launch(void* const* d_in, const int* in_sizes, int n_in,
                              void* d_out, int out_size, void* d_ws, size_t ws_size,
                              hipStream_t stream) {
    const float* inputs = (const float*)d_in[0];
    const int* targets  = (const int*)d_in[1];
    const float* weight = (const float*)d_in[3];

    const int N = in_sizes[1];                 // 65536
    const int D = in_sizes[0] / N;             // 1024
    const int C = in_sizes[3] / D;             // 1000
    const int D4 = D / 4;                      // 256

    int* counts  = (int*)d_ws;
    int* cursors = counts + C;
    int* offsets = cursors + C;
    int* binned  = offsets + C;
    float* part  = (float*)(binned + N);

    // 1. fused zero + histogram + scan + cursor init (single block)
    hist_scan_kernel<<<1, 1024, 0, stream>>>(targets, N, C, counts, offsets, cursors);

    // 2. scatter row ids into bins
    scatter_kernel<<<(N + 255) / 256, 256, 0, stream>>>(targets, cursors, binned, N);

    // 3. per-(class,quarter) gather-reduce -> partials
    gather_kernel<<<SPLIT * C, D4, 0, stream>>>(
        (const floatx4*)inputs, counts, offsets, binned, (floatx4*)part, D4);

    // 4. combine partials + mean / weight fallback
    finalize_kernel<<<C, D4, 0, stream>>>(
        (const floatx4*)part, (const floatx4*)weight, counts, (floatx4*)d_out, D4);
}

// Round 9
// 378.312 us; speedup vs baseline: 1.1129x; 1.1129x over previous
//
#include <hip/hip_runtime.h>

// Segment-mean ("centers") via bin-then-gather (no atomics on the heavy pass).
// inputs: [N, D] f32, targets: [N] i32, classes: scalar (derived), class_weight: [C, D] f32
// out: [C, D] f32
// ws: counts i32[C] | cursors i32[C] | offsets i32[C] | binned i32[N]
//
// Time budget (MI355X): harness reset (1 GiB ws poison ~161 us + 252 MB input
// restore ~80 us + misc) ~290 us is charged into dur_us and is not controllable.
// Chain floor: gather ~41 us (256 MB @ 6.3 TB/s) + ~15 us bookkeeping.
// Measured history: scatter-atomic 1178 | bin-gather SPLIT=2+nt 391..412 |
// fused-hist SPLIT=4 plain 421. Noise band ~±25 us.

typedef float floatx4 __attribute__((ext_vector_type(4)));

__global__ void zero_kernel(int* __restrict__ p, int n) {
    int i = blockIdx.x * blockDim.x + threadIdx.x;
    if (i < n) p[i] = 0;
}

// Parallel histogram — whole-chip, global atomics on 1000 L2-resident counters.
__global__ void count_kernel(const int* __restrict__ targets, int* __restrict__ counts, int n) {
    int i = blockIdx.x * blockDim.x + threadIdx.x;
    if (i < n) atomicAdd(&counts[targets[i]], 1);
}

// Single-block exclusive scan (Hillis-Steele); also seeds cursors. C <= 1024.
__global__ void scan_kernel(const int* __restrict__ counts,
                            int* __restrict__ offsets,
                            int* __restrict__ cursors, int c) {
    __shared__ int buf[2][1024];
    int tid = threadIdx.x;
    int v = (tid < c) ? counts[tid] : 0;
    buf[0][tid] = v;
    __syncthreads();
    int src = 0;
    for (int d = 1; d < 1024; d <<= 1) {
        int x = buf[src][tid];
        if (tid >= d) x += buf[src][tid - d];
        buf[src ^ 1][tid] = x;
        src ^= 1;
        __syncthreads();
    }
    if (tid < c) {
        int excl = buf[src][tid] - v;   // exclusive prefix
        offsets[tid] = excl;
        cursors[tid] = excl;            // scatter bumps from here
    }
}

__global__ void scatter_kernel(const int* __restrict__ targets,
                               int* __restrict__ cursors,
                               int* __restrict__ binned, int n) {
    int i = blockIdx.x * blockDim.x + threadIdx.x;
    if (i < n) {
        int pos = atomicAdd(&cursors[targets[i]], 1);   // cursor pre-seeded with offset
        binned[pos] = i;
    }
}

// One block per class; 256 threads x float4 = one full 4 KB row per iteration.
// 1000 blocks x 4 waves = 16 waves/CU; with 8 x 16B loads in flight per thread
// that's ~128 KB in flight per CU >> the ~9 KB Little's-law requirement for
// 6.3 TB/s at ~375 ns latency. Mean + weight-fallback fused here (no partials).
__global__ void gather_finalize_kernel(const floatx4* __restrict__ in4,
                                       const floatx4* __restrict__ w4,
                                       const int* __restrict__ counts,
                                       const int* __restrict__ offsets,
                                       const int* __restrict__ binned,
                                       floatx4* __restrict__ out4, int d4) {
    int c = blockIdx.x;
    int tid = threadIdx.x;                     // 0..255 == d4
    size_t obase = (size_t)c * d4 + tid;
    int cnt = counts[c];
    if (cnt == 0) {                            // absent class -> class_weight row
        out4[obase] = w4[obase];
        return;
    }
    int off = offsets[c];

    __shared__ int rows[1024];
    floatx4 a0 = {0,0,0,0}, a1 = {0,0,0,0}, a2 = {0,0,0,0}, a3 = {0,0,0,0};
    floatx4 a4 = {0,0,0,0}, a5 = {0,0,0,0}, a6 = {0,0,0,0}, a7 = {0,0,0,0};

    for (int base = 0; base < cnt; base += 1024) {
        int mm = min(cnt - base, 1024);
        __syncthreads();
        for (int j = tid; j < mm; j += blockDim.x) rows[j] = binned[off + base + j];
        __syncthreads();
        int j = 0;
        for (; j + 7 < mm; j += 8) {           // 8 independent load chains
            int r0 = rows[j],   r1 = rows[j+1], r2 = rows[j+2], r3 = rows[j+3];
            int r4 = rows[j+4], r5 = rows[j+5], r6 = rows[j+6], r7 = rows[j+7];
            a0 += __builtin_nontemporal_load(&in4[(size_t)r0 * d4 + tid]);
            a1 += __builtin_nontemporal_load(&in4[(size_t)r1 * d4 + tid]);
            a2 += __builtin_nontemporal_load(&in4[(size_t)r2 * d4 + tid]);
            a3 += __builtin_nontemporal_load(&in4[(size_t)r3 * d4 + tid]);
            a4 += __builtin_nontemporal_load(&in4[(size_t)r4 * d4 + tid]);
            a5 += __builtin_nontemporal_load(&in4[(size_t)r5 * d4 + tid]);
            a6 += __builtin_nontemporal_load(&in4[(size_t)r6 * d4 + tid]);
            a7 += __builtin_nontemporal_load(&in4[(size_t)r7 * d4 + tid]);
        }
        for (; j < mm; ++j)
            a0 += __builtin_nontemporal_load(&in4[(size_t)rows[j] * d4 + tid]);
    }
    floatx4 s = ((a0 + a1) + (a2 + a3)) + ((a4 + a5) + (a6 + a7));
    out4[obase] = s * (1.0f / (float)cnt);
}

extern "C" void kernel_launch(void* const* d_in, const int* in_sizes, int n_in,
                              void* d_out, int out_size, void* d_ws, size_t ws_size,
                              hipStream_t stream) {
    const float* inputs = (const float*)d_in[0];
    const int* targets  = (const int*)d_in[1];
    const float* weight = (const float*)d_in[3];

    const int N = in_sizes[1];                 // 65536
    const int D = in_sizes[0] / N;             // 1024
    const int C = in_sizes[3] / D;             // 1000
    const int D4 = D / 4;                      // 256

    int* counts  = (int*)d_ws;
    int* cursors = counts + C;
    int* offsets = cursors + C;
    int* binned  = offsets + C;

    // 1. zero counts (cursors are seeded by scan; ws is re-poisoned each call)
    zero_kernel<<<(C + 255) / 256, 256, 0, stream>>>(counts, C);

    // 2. histogram of targets (whole-chip parallel)
    count_kernel<<<(N + 255) / 256, 256, 0, stream>>>(targets, counts, N);

    // 3. exclusive prefix sum -> offsets, seed cursors
    scan_kernel<<<1, 1024, 0, stream>>>(counts, offsets, cursors, C);

    // 4. scatter row ids into bins
    scatter_kernel<<<(N + 255) / 256, 256, 0, stream>>>(targets, cursors, binned, N);

    // 5. per-class gather-reduce + mean / weight fallback (fused finalize)
    gather_finalize_kernel<<<C, D4, 0, stream>>>(
        (const floatx4*)inputs, (const floatx4*)weight,
        counts, offsets, binned, (floatx4*)d_out, D4);
}